// Round 1
// baseline (543.673 us; speedup 1.0000x reference)
//
#include <hip/hip_runtime.h>
#include <hip/hip_bf16.h>

#define NVOX 200000
#define CCH  128
#define KTOT 384
#define EPS_BN 1e-5f
#define PB   625          // persistent blocks per axis
#define TPB  5            // tiles per block (625*5 = 3125 = 200000/64)

typedef __bf16 bf16x8 __attribute__((ext_vector_type(8)));
typedef float  floatx4 __attribute__((ext_vector_type(4)));

// ---- workspace layout (bytes) ----
#define XBF_OFF    0ull
#define XBF_BYTES  ((size_t)(NVOX + 1) * CCH * 2)      // bf16 features + zero row
#define WT_OFF     (XBF_OFF + XBF_BYTES)
#define WT_BYTES   ((size_t)3 * CCH * KTOT * 2)        // WT[a][c][k] bf16
#define OUTB_OFF   (WT_OFF + WT_BYTES)
#define OUTB_BYTES ((size_t)3 * NVOX * CCH * 2)        // pre-BN out, bf16
#define STATS_OFF  (OUTB_OFF + OUTB_BYTES)
#define STATS_BYTES ((size_t)3 * 2 * CCH * 4)          // sum/sumsq fp32

// Cast features -> bf16, append one zero row at index NVOX (sentinel gathers read zeros).
__global__ void k_prep_x(const float* __restrict__ xf, __bf16* __restrict__ xbf) {
    int idx = blockIdx.x * blockDim.x + threadIdx.x;   // one 8-channel chunk
    const int total = (NVOX + 1) * 16;
    if (idx >= total) return;
    float v[8];
    if (idx < NVOX * 16) {
        const float4* p = (const float4*)xf + (size_t)idx * 2;
        float4 f0 = p[0], f1 = p[1];
        v[0] = f0.x; v[1] = f0.y; v[2] = f0.z; v[3] = f0.w;
        v[4] = f1.x; v[5] = f1.y; v[6] = f1.z; v[7] = f1.w;
    } else {
        #pragma unroll
        for (int j = 0; j < 8; ++j) v[j] = 0.0f;
    }
    bf16x8 o;
    #pragma unroll
    for (int j = 0; j < 8; ++j) o[j] = (__bf16)v[j];
    *((bf16x8*)xbf + idx) = o;
}

// W[3][3][C][C] (k,c) -> WT[3][C][KTOT] bf16 where k = s*128 + k0 (prev|self|next concat).
__global__ void k_prep_w(const float* __restrict__ W, __bf16* __restrict__ wt) {
    int idx = blockIdx.x * blockDim.x + threadIdx.x;
    if (idx >= 3 * CCH * KTOT) return;
    int k = idx % KTOT; int rem = idx / KTOT;
    int c = rem % CCH;  int a = rem / CCH;
    int s = k >> 7, k0 = k & 127;
    wt[idx] = (__bf16)W[(((size_t)(a * 3 + s) * CCH) + k0) * CCH + c];
}

// Persistent-block GEMM, software-pipelined.
// Per tile: [write prefetched A regs -> smemA] bar [issue gather for ti+1 into regs]
// [MFMA on smemA] [stats -> register accumulators] [acc -> smemO] bar [smemO -> global].
// Gather latency for ti+1 drains at the post-MFMA barrier instead of pre-MFMA.
// Stats atomics hoisted out of the loop entirely (1 set per block, at the end) --
// removes the contended-atomic vmcnt drain from every per-tile barrier.
__launch_bounds__(256, 2)
__global__ void k_gemm(const __bf16* __restrict__ xbf, const __bf16* __restrict__ wt,
                       const int* __restrict__ nb, __bf16* __restrict__ outb,
                       float* __restrict__ stats) {
    __shared__ __bf16 smemA[64 * 392];   // A tile (64 x 384, stride 392)
    __shared__ __bf16 smemO[64 * 136];   // bf16 out staging (disjoint from A)
    __shared__ int s_pn[2][128];         // double-buffered prev/next row indices

    const int a    = blockIdx.y;
    const int tid  = threadIdx.x;
    const int w    = tid >> 6;
    const int lane = tid & 63;
    const int q    = lane >> 4;
    const int ln   = lane & 15;

    // ---- B resident in registers for the whole block lifetime ----
    const __bf16* wbase = wt + (size_t)a * CCH * KTOT;
    bf16x8 B0[12], B1[12];
    #pragma unroll
    for (int ks = 0; ks < 12; ++ks) {
        B0[ks] = *(const bf16x8*)(wbase + (size_t)(w * 32 + ln) * KTOT + ks * 32 + q * 8);
        B1[ks] = *(const bf16x8*)(wbase + (size_t)(w * 32 + 16 + ln) * KTOT + ks * 32 + q * 8);
    }

    // per-column stats accumulated in registers across all tiles
    float s0 = 0.f, ss0 = 0.f, s1 = 0.f, ss1 = 0.f;

    // ---- prologue: pn + gather for tile 0; issue pn for tile 1 ----
    int r_pn = 0;
    if (tid < 128) {
        r_pn = nb[(size_t)(a * 2 + (tid >> 6)) * NVOX + blockIdx.x * 64 + (tid & 63)];
        s_pn[0][tid] = r_pn;
    }
    __syncthreads();

    bf16x8 areg[12];
    {
        const int row0 = blockIdx.x * 64;
        #pragma unroll
        for (int it = 0; it < 12; ++it) {
            int cc  = it * 256 + tid;
            int r   = cc / 48;
            int seg = cc - r * 48;
            int src = seg >> 4, ch = seg & 15;
            int g = (src == 1) ? (row0 + r) : s_pn[0][(src >> 1) * 64 + r];
            areg[it] = *(const bf16x8*)(xbf + (size_t)g * CCH + ch * 8);
        }
    }
    if (tid < 128)
        r_pn = nb[(size_t)(a * 2 + (tid >> 6)) * NVOX + (blockIdx.x + PB) * 64 + (tid & 63)];

    #pragma unroll
    for (int ti = 0; ti < TPB; ++ti) {
        const int row0 = (blockIdx.x + ti * PB) * 64;
        const int buf  = ti & 1;

        // ---- publish prefetched A tile + next tile's pn ----
        #pragma unroll
        for (int it = 0; it < 12; ++it) {
            int cc  = it * 256 + tid;
            int r   = cc / 48;
            int seg = cc - r * 48;
            *(bf16x8*)(&smemA[r * 392 + seg * 8]) = areg[it];
        }
        if (ti + 1 < TPB && tid < 128) s_pn[buf ^ 1][tid] = r_pn;
        __syncthreads();

        // ---- issue gather for tile ti+1 (in flight across the MFMA loop) ----
        bf16x8 areg2[12];
        if (ti + 1 < TPB) {
            const int rown = (blockIdx.x + (ti + 1) * PB) * 64;
            #pragma unroll
            for (int it = 0; it < 12; ++it) {
                int cc  = it * 256 + tid;
                int r   = cc / 48;
                int seg = cc - r * 48;
                int src = seg >> 4, ch = seg & 15;
                int g = (src == 1) ? (rown + r) : s_pn[buf ^ 1][(src >> 1) * 64 + r];
                areg2[it] = *(const bf16x8*)(xbf + (size_t)g * CCH + ch * 8);
            }
            if (ti + 2 < TPB && tid < 128)
                r_pn = nb[(size_t)(a * 2 + (tid >> 6)) * NVOX
                          + (blockIdx.x + (ti + 2) * PB) * 64 + (tid & 63)];
        }

        // ---- MFMA K-loop: LDS A frags x register B frags ----
        floatx4 acc0[4], acc1[4];
        #pragma unroll
        for (int mt = 0; mt < 4; ++mt)
            #pragma unroll
            for (int r = 0; r < 4; ++r) { acc0[mt][r] = 0.0f; acc1[mt][r] = 0.0f; }

        #pragma unroll
        for (int ks = 0; ks < 12; ++ks) {
            #pragma unroll
            for (int mt = 0; mt < 4; ++mt) {
                bf16x8 afr = *(const bf16x8*)(&smemA[(mt * 16 + ln) * 392 + ks * 32 + q * 8]);
                acc0[mt] = __builtin_amdgcn_mfma_f32_16x16x32_bf16(afr, B0[ks], acc0[mt], 0, 0, 0);
                acc1[mt] = __builtin_amdgcn_mfma_f32_16x16x32_bf16(afr, B1[ks], acc1[mt], 0, 0, 0);
            }
        }

        // ---- stats into register accumulators (no atomics in the loop) ----
        #pragma unroll
        for (int mt = 0; mt < 4; ++mt)
            #pragma unroll
            for (int r = 0; r < 4; ++r) {
                float v0 = acc0[mt][r]; s0 += v0; ss0 += v0 * v0;
                float v1 = acc1[mt][r]; s1 += v1; ss1 += v1 * v1;
            }

        // ---- bf16 out tile via smemO (disjoint region: no pre-barrier needed) ----
        #pragma unroll
        for (int mt = 0; mt < 4; ++mt) {
            #pragma unroll
            for (int r = 0; r < 4; ++r) {
                int rr = mt * 16 + q * 4 + r;
                smemO[rr * 136 + w * 32 + ln]      = (__bf16)acc0[mt][r];
                smemO[rr * 136 + w * 32 + 16 + ln] = (__bf16)acc1[mt][r];
            }
        }
        __syncthreads();   // out tile published; also guarantees all A-reads done

        #pragma unroll
        for (int it2 = 0; it2 < 4; ++it2) {
            int i = it2 * 256 + tid;         // 1024 chunks of 8 bf16
            int r = i >> 4, ch = i & 15;
            bf16x8 v = *(const bf16x8*)(&smemO[r * 136 + ch * 8]);
            *(bf16x8*)(outb + ((size_t)a * NVOX + row0 + r) * CCH + ch * 8) = v;
        }

        if (ti + 1 < TPB) {
            #pragma unroll
            for (int it = 0; it < 12; ++it) areg[it] = areg2[it];
        }
    }

    // ---- epilogue: quad-reduce stats, one atomic set per block ----
    s0 += __shfl_xor(s0, 16); ss0 += __shfl_xor(ss0, 16);
    s0 += __shfl_xor(s0, 32); ss0 += __shfl_xor(ss0, 32);
    s1 += __shfl_xor(s1, 16); ss1 += __shfl_xor(ss1, 16);
    s1 += __shfl_xor(s1, 32); ss1 += __shfl_xor(ss1, 32);
    if (lane < 16) {
        int c0 = w * 32 + lane, c1 = w * 32 + 16 + lane;
        atomicAdd(&stats[a * 2 * CCH + c0], s0);
        atomicAdd(&stats[a * 2 * CCH + CCH + c0], ss0);
        atomicAdd(&stats[a * 2 * CCH + c1], s1);
        atomicAdd(&stats[a * 2 * CCH + CCH + c1], ss1);
    }
}

// out[i,c] = features[i,c] * sum_a sigmoid(outb[a,i,c]*sc + sh)
__launch_bounds__(256)
__global__ void k_final(const __bf16* __restrict__ outb, const float* __restrict__ xf,
                        const float* __restrict__ stats, const float* __restrict__ gamma,
                        const float* __restrict__ beta, float* __restrict__ out) {
    __shared__ float lsc[384], lsh[384];
    int tid = threadIdx.x;
    for (int i = tid; i < 384; i += 256) {
        int a = i >> 7, c = i & 127;
        float mu  = stats[a * 256 + c] * (1.0f / NVOX);
        float var = stats[a * 256 + 128 + c] * (1.0f / NVOX) - mu * mu;
        float rs  = rsqrtf(var + EPS_BN);
        float g = gamma[i], b = beta[i];
        lsc[i] = rs * g;
        lsh[i] = b - mu * rs * g;
    }
    __syncthreads();
    const int total = NVOX * 16;
    for (int idx = blockIdx.x * 256 + tid; idx < total; idx += gridDim.x * 256) {
        int c0 = (idx & 15) * 8;
        float4 f0 = ((const float4*)xf)[(size_t)idx * 2];
        float4 f1 = ((const float4*)xf)[(size_t)idx * 2 + 1];
        float r[8];
        #pragma unroll
        for (int j = 0; j < 8; ++j) r[j] = 0.0f;
        #pragma unroll
        for (int a = 0; a < 3; ++a) {
            bf16x8 o = *((const bf16x8*)outb + (size_t)a * NVOX * 16 + idx);
            #pragma unroll
            for (int j = 0; j < 8; ++j) {
                float v = (float)o[j] * lsc[a * 128 + c0 + j] + lsh[a * 128 + c0 + j];
                r[j] += __builtin_amdgcn_rcpf(1.0f + __expf(-v));
            }
        }
        float4 o0, o1;
        o0.x = r[0] * f0.x; o0.y = r[1] * f0.y; o0.z = r[2] * f0.z; o0.w = r[3] * f0.w;
        o1.x = r[4] * f1.x; o1.y = r[5] * f1.y; o1.z = r[6] * f1.z; o1.w = r[7] * f1.w;
        ((float4*)out)[(size_t)idx * 2]     = o0;
        ((float4*)out)[(size_t)idx * 2 + 1] = o1;
    }
}

extern "C" void kernel_launch(void* const* d_in, const int* in_sizes, int n_in,
                              void* d_out, int out_size, void* d_ws, size_t ws_size,
                              hipStream_t stream) {
    const float* xf    = (const float*)d_in[0];
    const int*   nb    = (const int*)  d_in[1];
    const float* W     = (const float*)d_in[2];
    const float* gamma = (const float*)d_in[3];
    const float* beta  = (const float*)d_in[4];
    float* out = (float*)d_out;

    char* ws = (char*)d_ws;
    __bf16* xbf   = (__bf16*)(ws + XBF_OFF);
    __bf16* wt    = (__bf16*)(ws + WT_OFF);
    __bf16* outb  = (__bf16*)(ws + OUTB_OFF);
    float*  stats = (float*)(ws + STATS_OFF);

    hipMemsetAsync(stats, 0, STATS_BYTES, stream);
    k_prep_x<<<((NVOX + 1) * 16 + 255) / 256, 256, 0, stream>>>(xf, xbf);
    k_prep_w<<<(3 * CCH * KTOT + 255) / 256, 256, 0, stream>>>(W, wt);
    k_gemm<<<dim3(PB, 3), 256, 0, stream>>>(xbf, wt, nb, outb, stats);
    k_final<<<2048, 256, 0, stream>>>(outb, xf, stats, gamma, beta, out);
}

// Round 2
// 359.048 us; speedup vs baseline: 1.5142x; 1.5142x over previous
//
#include <hip/hip_runtime.h>
#include <hip/hip_bf16.h>

#define NVOX 200000
#define CCH  128
#define KTOT 384
#define EPS_BN 1e-5f
#define PB   625          // persistent blocks per axis
#define TPB  5            // tiles per block (625*5 = 3125 = 200000/64)

typedef __bf16 bf16x8 __attribute__((ext_vector_type(8)));
typedef float  floatx4 __attribute__((ext_vector_type(4)));

// ---- workspace layout (bytes) ----
#define XBF_OFF    0ull
#define XBF_BYTES  ((size_t)(NVOX + 1) * CCH * 2)      // bf16 features + zero row
#define WT_OFF     (XBF_OFF + XBF_BYTES)
#define WT_BYTES   ((size_t)3 * CCH * KTOT * 2)        // WT[a][c][k] bf16
#define OUTB_OFF   (WT_OFF + WT_BYTES)
#define OUTB_BYTES ((size_t)3 * NVOX * CCH * 2)        // pre-BN out, bf16
#define STATS_OFF  (OUTB_OFF + OUTB_BYTES)
#define STATS_BYTES ((size_t)3 * 2 * CCH * 4)          // sum/sumsq fp32

// Cast features -> bf16, append one zero row at index NVOX (sentinel gathers read zeros).
__global__ void k_prep_x(const float* __restrict__ xf, __bf16* __restrict__ xbf) {
    int idx = blockIdx.x * blockDim.x + threadIdx.x;   // one 8-channel chunk
    const int total = (NVOX + 1) * 16;
    if (idx >= total) return;
    float v[8];
    if (idx < NVOX * 16) {
        const float4* p = (const float4*)xf + (size_t)idx * 2;
        float4 f0 = p[0], f1 = p[1];
        v[0] = f0.x; v[1] = f0.y; v[2] = f0.z; v[3] = f0.w;
        v[4] = f1.x; v[5] = f1.y; v[6] = f1.z; v[7] = f1.w;
    } else {
        #pragma unroll
        for (int j = 0; j < 8; ++j) v[j] = 0.0f;
    }
    bf16x8 o;
    #pragma unroll
    for (int j = 0; j < 8; ++j) o[j] = (__bf16)v[j];
    *((bf16x8*)xbf + idx) = o;
}

// W[3][3][C][C] (k,c) -> WT[3][C][KTOT] bf16 where k = s*128 + k0 (prev|self|next concat).
__global__ void k_prep_w(const float* __restrict__ W, __bf16* __restrict__ wt) {
    int idx = blockIdx.x * blockDim.x + threadIdx.x;
    if (idx >= 3 * CCH * KTOT) return;
    int k = idx % KTOT; int rem = idx / KTOT;
    int c = rem % CCH;  int a = rem / CCH;
    int s = k >> 7, k0 = k & 127;
    wt[idx] = (__bf16)W[(((size_t)(a * 3 + s) * CCH) + k0) * CCH + c];
}

// Persistent-block GEMM.
// Staging via global_load_lds: per-lane gathered global srcs, linear LDS dest
// (wave-uniform base + lane*16). A tile unpadded [64][384]; bank conflicts on the
// MFMA ds_read_b128 fixed by XOR-swizzling the 16B-chunk index with (row&7) on
// BOTH the source side (which global chunk a lane fetches) and the read side.
// 2 barriers/tile: (c) after glds issue (vmcnt drain -> tile ready; also orders
// prev tile's smemO reads vs this tile's writes), (e) after smemO write (also
// guarantees all A-reads done before next tile's glds overwrite).
// Stats accumulate in registers; one atomic set per block at the end.
// nb row-index prefetch issued AFTER (c) so its HBM latency drains at (e),
// hidden under the MFMA loop.
__launch_bounds__(256, 2)
__global__ void k_gemm(const __bf16* __restrict__ xbf, const __bf16* __restrict__ wt,
                       const int* __restrict__ nb, __bf16* __restrict__ outb,
                       float* __restrict__ stats) {
    __shared__ __align__(16) __bf16 smemA[64 * 384];   // A tile, linear (glds dest)
    __shared__ __align__(16) __bf16 smemO[64 * 136];   // bf16 out staging (disjoint)
    __shared__ int s_pn[2][128];                       // double-buffered prev/next idx

    const int a    = blockIdx.y;
    const int tid  = threadIdx.x;
    const int w    = tid >> 6;
    const int lane = tid & 63;
    const int q    = lane >> 4;
    const int ln   = lane & 15;
    const int e    = ln & 7;       // row-XOR key for this lane's fragment rows

    // ---- B resident in registers for the whole block lifetime ----
    const __bf16* wbase = wt + (size_t)a * CCH * KTOT;
    bf16x8 B0[12], B1[12];
    #pragma unroll
    for (int ks = 0; ks < 12; ++ks) {
        B0[ks] = *(const bf16x8*)(wbase + (size_t)(w * 32 + ln) * KTOT + ks * 32 + q * 8);
        B1[ks] = *(const bf16x8*)(wbase + (size_t)(w * 32 + 16 + ln) * KTOT + ks * 32 + q * 8);
    }

    // per-column stats accumulated in registers across all tiles
    float s0 = 0.f, ss0 = 0.f, s1 = 0.f, ss1 = 0.f;

    // ---- prologue: pn for tile 0 published; pn for tile 1 in r_pn ----
    int r_pn = 0;
    if (tid < 128) {
        const size_t nbase = (size_t)(a * 2 + (tid >> 6)) * NVOX + (tid & 63);
        r_pn = nb[nbase + blockIdx.x * 64];
        s_pn[0][tid] = r_pn;
        r_pn = nb[nbase + (blockIdx.x + PB) * 64];
    }
    __syncthreads();

    for (int ti = 0; ti < TPB; ++ti) {
        const int row0 = (blockIdx.x + ti * PB) * 64;
        const int buf  = ti & 1;

        // ---- issue gathered A tile straight into LDS (3072 x 16B chunks) ----
        #pragma unroll
        for (int it = 0; it < 12; ++it) {
            int p    = it * 256 + tid;       // linear LDS chunk index
            int r    = p / 48;               // row 0..63
            int spos = p - r * 48;           // swizzled slot within row
            int slog = spos ^ (r & 7);       // logical chunk: src*16 + ch
            int src  = slog >> 4, ch = slog & 15;
            int g    = (src == 1) ? (row0 + r) : s_pn[buf][(src >> 1) * 64 + r];
            const __bf16* gp = xbf + (size_t)g * CCH + ch * 8;
            __builtin_amdgcn_global_load_lds(
                (const __attribute__((address_space(1))) void*)gp,
                (__attribute__((address_space(3))) void*)(&smemA[(it * 256 + w * 64) * 8]),
                16, 0, 0);
        }
        if (ti + 1 < TPB && tid < 128) s_pn[buf ^ 1][tid] = r_pn;
        __syncthreads();   // (c): A tile landed; s_pn[buf^1] visible; prev smemO reads done

        // prefetch pn for tile ti+2 (drains at (e), hidden under MFMA)
        if (ti + 2 < TPB && tid < 128)
            r_pn = nb[(size_t)(a * 2 + (tid >> 6)) * NVOX
                      + (blockIdx.x + (ti + 2) * PB) * 64 + (tid & 63)];

        // ---- MFMA K-loop: swizzled LDS A frags x register B frags ----
        floatx4 acc0[4], acc1[4];
        #pragma unroll
        for (int mt = 0; mt < 4; ++mt)
            #pragma unroll
            for (int r = 0; r < 4; ++r) { acc0[mt][r] = 0.0f; acc1[mt][r] = 0.0f; }

        #pragma unroll
        for (int ks = 0; ks < 12; ++ks) {
            #pragma unroll
            for (int mt = 0; mt < 4; ++mt) {
                int rr = mt * 16 + ln;
                int sp = (ks * 4 + q) ^ e;   // swizzled chunk slot
                bf16x8 afr = *(const bf16x8*)(&smemA[rr * 384 + sp * 8]);
                acc0[mt] = __builtin_amdgcn_mfma_f32_16x16x32_bf16(afr, B0[ks], acc0[mt], 0, 0, 0);
                acc1[mt] = __builtin_amdgcn_mfma_f32_16x16x32_bf16(afr, B1[ks], acc1[mt], 0, 0, 0);
            }
        }

        // ---- stats into register accumulators (no atomics in the loop) ----
        #pragma unroll
        for (int mt = 0; mt < 4; ++mt)
            #pragma unroll
            for (int r = 0; r < 4; ++r) {
                float v0 = acc0[mt][r]; s0 += v0; ss0 += v0 * v0;
                float v1 = acc1[mt][r]; s1 += v1; ss1 += v1 * v1;
            }

        // ---- bf16 out tile via smemO (disjoint region) ----
        #pragma unroll
        for (int mt = 0; mt < 4; ++mt) {
            #pragma unroll
            for (int r = 0; r < 4; ++r) {
                int rr = mt * 16 + q * 4 + r;
                smemO[rr * 136 + w * 32 + ln]      = (__bf16)acc0[mt][r];
                smemO[rr * 136 + w * 32 + 16 + ln] = (__bf16)acc1[mt][r];
            }
        }
        __syncthreads();   // (e): smemO published; all A-reads complete

        #pragma unroll
        for (int it2 = 0; it2 < 4; ++it2) {
            int i = it2 * 256 + tid;         // 1024 chunks of 8 bf16
            int r = i >> 4, ch = i & 15;
            bf16x8 v = *(const bf16x8*)(&smemO[r * 136 + ch * 8]);
            *(bf16x8*)(outb + ((size_t)a * NVOX + row0 + r) * CCH + ch * 8) = v;
        }
        // next iteration's (c) barrier orders these smemO reads vs the next writes
    }

    // ---- epilogue: quad-reduce stats, one atomic set per block ----
    s0 += __shfl_xor(s0, 16); ss0 += __shfl_xor(ss0, 16);
    s0 += __shfl_xor(s0, 32); ss0 += __shfl_xor(ss0, 32);
    s1 += __shfl_xor(s1, 16); ss1 += __shfl_xor(ss1, 16);
    s1 += __shfl_xor(s1, 32); ss1 += __shfl_xor(ss1, 32);
    if (lane < 16) {
        int c0 = w * 32 + lane, c1 = w * 32 + 16 + lane;
        atomicAdd(&stats[a * 2 * CCH + c0], s0);
        atomicAdd(&stats[a * 2 * CCH + CCH + c0], ss0);
        atomicAdd(&stats[a * 2 * CCH + c1], s1);
        atomicAdd(&stats[a * 2 * CCH + CCH + c1], ss1);
    }
}

// out[i,c] = features[i,c] * sum_a sigmoid(outb[a,i,c]*sc + sh)
__launch_bounds__(256)
__global__ void k_final(const __bf16* __restrict__ outb, const float* __restrict__ xf,
                        const float* __restrict__ stats, const float* __restrict__ gamma,
                        const float* __restrict__ beta, float* __restrict__ out) {
    __shared__ float lsc[384], lsh[384];
    int tid = threadIdx.x;
    for (int i = tid; i < 384; i += 256) {
        int a = i >> 7, c = i & 127;
        float mu  = stats[a * 256 + c] * (1.0f / NVOX);
        float var = stats[a * 256 + 128 + c] * (1.0f / NVOX) - mu * mu;
        float rs  = rsqrtf(var + EPS_BN);
        float g = gamma[i], b = beta[i];
        lsc[i] = rs * g;
        lsh[i] = b - mu * rs * g;
    }
    __syncthreads();
    const int total = NVOX * 16;
    for (int idx = blockIdx.x * 256 + tid; idx < total; idx += gridDim.x * 256) {
        int c0 = (idx & 15) * 8;
        float4 f0 = ((const float4*)xf)[(size_t)idx * 2];
        float4 f1 = ((const float4*)xf)[(size_t)idx * 2 + 1];
        float r[8];
        #pragma unroll
        for (int j = 0; j < 8; ++j) r[j] = 0.0f;
        #pragma unroll
        for (int a = 0; a < 3; ++a) {
            bf16x8 o = *((const bf16x8*)outb + (size_t)a * NVOX * 16 + idx);
            #pragma unroll
            for (int j = 0; j < 8; ++j) {
                float v = (float)o[j] * lsc[a * 128 + c0 + j] + lsh[a * 128 + c0 + j];
                r[j] += __builtin_amdgcn_rcpf(1.0f + __expf(-v));
            }
        }
        float4 o0, o1;
        o0.x = r[0] * f0.x; o0.y = r[1] * f0.y; o0.z = r[2] * f0.z; o0.w = r[3] * f0.w;
        o1.x = r[4] * f1.x; o1.y = r[5] * f1.y; o1.z = r[6] * f1.z; o1.w = r[7] * f1.w;
        ((float4*)out)[(size_t)idx * 2]     = o0;
        ((float4*)out)[(size_t)idx * 2 + 1] = o1;
    }
}

extern "C" void kernel_launch(void* const* d_in, const int* in_sizes, int n_in,
                              void* d_out, int out_size, void* d_ws, size_t ws_size,
                              hipStream_t stream) {
    const float* xf    = (const float*)d_in[0];
    const int*   nb    = (const int*)  d_in[1];
    const float* W     = (const float*)d_in[2];
    const float* gamma = (const float*)d_in[3];
    const float* beta  = (const float*)d_in[4];
    float* out = (float*)d_out;

    char* ws = (char*)d_ws;
    __bf16* xbf   = (__bf16*)(ws + XBF_OFF);
    __bf16* wt    = (__bf16*)(ws + WT_OFF);
    __bf16* outb  = (__bf16*)(ws + OUTB_OFF);
    float*  stats = (float*)(ws + STATS_OFF);

    hipMemsetAsync(stats, 0, STATS_BYTES, stream);
    k_prep_x<<<((NVOX + 1) * 16 + 255) / 256, 256, 0, stream>>>(xf, xbf);
    k_prep_w<<<(3 * CCH * KTOT + 255) / 256, 256, 0, stream>>>(W, wt);
    k_gemm<<<dim3(PB, 3), 256, 0, stream>>>(xbf, wt, nb, outb, stats);
    k_final<<<2048, 256, 0, stream>>>(outb, xf, stats, gamma, beta, out);
}